// Round 6
// baseline (341.038 us; speedup 1.0000x reference)
//
#include <hip/hip_runtime.h>
#include <hip/hip_bf16.h>

constexpr int TTOK  = 16384;   // B*S = 8*2048
constexpr int DDIM  = 512;
constexpr int FFDIM = 2048;
constexpr int NEXP  = 8;
constexpr int GB_TOK = 16;             // tokens per gate/scatter block
constexpr int NGB    = TTOK / GB_TOK;  // 1024
constexpr int MAXTILES = TTOK / 128 + NEXP;  // 136: worst-case M-tiles over all experts

typedef __attribute__((ext_vector_type(8))) short short8_t;
typedef __attribute__((ext_vector_type(4))) float f32x4_t;

__device__ __forceinline__ unsigned short f2bf(float f) {
    union { float f; unsigned u; } v; v.f = f;
    return (unsigned short)((v.u + 0x7fffu + ((v.u >> 16) & 1u)) >> 16);  // RNE
}

__device__ __forceinline__ void gl_lds16(const void* g, void* l) {
    __builtin_amdgcn_global_load_lds(
        (const __attribute__((address_space(1))) void*)g,
        (__attribute__((address_space(3))) void*)l,
        16, 0, 0);
}

// ---------------- vectorized transpose + fp32->bf16 cast, 64x64 tiles.
// float4 global loads, LDS stride-65 (odd stride -> <=2-way bank alias, free),
// short8 (16 B) coalesced stores. grid (256, 16): y<8 = W1 expert y, y>=8 = W2.
__global__ __launch_bounds__(256) void transpose_cvt2(const float* __restrict__ W1,
                                                      const float* __restrict__ W2,
                                                      unsigned short* __restrict__ W1T,
                                                      unsigned short* __restrict__ W2T) {
    __shared__ float lds[64 * 65];
    int z = blockIdx.y;
    bool isW2 = z >= NEXP;
    int e = isW2 ? z - NEXP : z;
    int R = isW2 ? FFDIM : DDIM;
    int C = isW2 ? DDIM : FFDIM;
    int tilesC = C / 64;
    int t = blockIdx.x;                       // 256 tiles per z
    int c0 = (t % tilesC) * 64;
    int r0 = (t / tilesC) * 64;
    const float* s = (isW2 ? W2 : W1) + (size_t)e * DDIM * FFDIM;
    unsigned short* d = (isW2 ? W2T : W1T) + (size_t)e * DDIM * FFDIM;
    int tid = threadIdx.x;
    int lr = tid >> 4, lc = (tid & 15) * 4;
    #pragma unroll
    for (int p = 0; p < 4; p++) {
        int r = p * 16 + lr;
        float4 v = *(const float4*)(s + (size_t)(r0 + r) * C + c0 + lc);
        lds[r * 65 + lc]     = v.x;
        lds[r * 65 + lc + 1] = v.y;
        lds[r * 65 + lc + 2] = v.z;
        lds[r * 65 + lc + 3] = v.w;
    }
    __syncthreads();
    int rr = (tid & 7) * 8, cbase = tid >> 3;
    #pragma unroll
    for (int p = 0; p < 2; p++) {
        int cc = p * 32 + cbase;
        union { short8_t v; unsigned short u[8]; } o;
        #pragma unroll
        for (int k = 0; k < 8; k++) o.u[k] = f2bf(lds[(rr + k) * 65 + cc]);
        *(short8_t*)(d + (size_t)(c0 + cc) * R + r0 + rr) = o.v;
    }
}

// ---------------- gating + fused scan (decoupled last-block pattern).
// Each block routes 16 tokens, publishes its expert histogram, then the LAST
// block to finish runs the 1024-block stable counting-sort scan and writes
// blockOffsets / segPrefix / tilePrefix.
__global__ __launch_bounds__(256) void gate_kernel(const float* __restrict__ x,
                                                   const float* __restrict__ Wg,
                                                   const float* __restrict__ bg,
                                                   int* __restrict__ route,
                                                   float* __restrict__ pmax,
                                                   int* __restrict__ blockCounts,
                                                   int* __restrict__ blockOffsets,
                                                   int* __restrict__ segPrefix,
                                                   int* __restrict__ tilePrefix,
                                                   int* __restrict__ doneCtr) {
    __shared__ int cnt[NEXP];
    __shared__ float bgs[NEXP];
    __shared__ int sc2[256][NEXP];   // scan workspace (winner block only)
    __shared__ int winner;
    int tid = threadIdx.x;
    if (tid < NEXP) { cnt[tid] = 0; bgs[tid] = bg[tid]; }
    __syncthreads();
    int wave = tid >> 6, lane = tid & 63;
    float w[8][8];
    #pragma unroll
    for (int jj = 0; jj < 8; jj++) {
        float4 a = *(const float4*)(Wg + (size_t)(lane * 8 + jj) * NEXP);
        float4 b = *(const float4*)(Wg + (size_t)(lane * 8 + jj) * NEXP + 4);
        w[jj][0] = a.x; w[jj][1] = a.y; w[jj][2] = a.z; w[jj][3] = a.w;
        w[jj][4] = b.x; w[jj][5] = b.y; w[jj][6] = b.z; w[jj][7] = b.w;
    }
    int tbase = blockIdx.x * GB_TOK + wave * 4;
    for (int it = 0; it < 4; it++) {
        int t = tbase + it;
        float4 xa = *(const float4*)(x + (size_t)t * DDIM + lane * 8);
        float4 xb = *(const float4*)(x + (size_t)t * DDIM + lane * 8 + 4);
        float xs[8] = {xa.x, xa.y, xa.z, xa.w, xb.x, xb.y, xb.z, xb.w};
        double acc[NEXP];
        #pragma unroll
        for (int e = 0; e < NEXP; e++) acc[e] = 0.0;
        #pragma unroll
        for (int jj = 0; jj < 8; jj++) {
            double xv = (double)xs[jj];
            #pragma unroll
            for (int e = 0; e < NEXP; e++) acc[e] += xv * (double)w[jj][e];
        }
        #pragma unroll
        for (int off = 32; off > 0; off >>= 1) {
            #pragma unroll
            for (int e = 0; e < NEXP; e++) acc[e] += __shfl_down(acc[e], off);
        }
        if (lane == 0) {
            double l[NEXP];
            #pragma unroll
            for (int e = 0; e < NEXP; e++) l[e] = acc[e] + (double)bgs[e];
            int r = 0; double lm = l[0];
            #pragma unroll
            for (int e = 1; e < NEXP; e++) if (l[e] > lm) { lm = l[e]; r = e; }
            double s = 0.0;
            #pragma unroll
            for (int e = 0; e < NEXP; e++) s += exp(l[e] - lm);
            route[t] = r;
            pmax[t] = (float)(1.0 / s);
            atomicAdd(&cnt[r], 1);
        }
    }
    __syncthreads();
    if (tid == 0) {
        #pragma unroll
        for (int e = 0; e < NEXP; e++) blockCounts[blockIdx.x * NEXP + e] = cnt[e];
        __threadfence();                                  // publish counts (device scope)
        winner = (atomicAdd(doneCtr, 1) == NGB - 1) ? 1 : 0;
    }
    __syncthreads();
    if (!winner) return;
    __threadfence();                                      // acquire side

    // ---- winner block: scan 1024 x 8 counts with 256 threads (4 blocks/thread)
    int tt[NEXP];
    #pragma unroll
    for (int e = 0; e < NEXP; e++) tt[e] = 0;
    #pragma unroll
    for (int j = 0; j < 4; j++)
        #pragma unroll
        for (int e = 0; e < NEXP; e++) tt[e] += blockCounts[(tid * 4 + j) * NEXP + e];
    #pragma unroll
    for (int e = 0; e < NEXP; e++) sc2[tid][e] = tt[e];
    __syncthreads();
    for (int off = 1; off < 256; off <<= 1) {
        int tv[NEXP];
        bool valid = tid >= off;
        if (valid) {
            #pragma unroll
            for (int e = 0; e < NEXP; e++) tv[e] = sc2[tid - off][e];
        }
        __syncthreads();
        if (valid) {
            #pragma unroll
            for (int e = 0; e < NEXP; e++) sc2[tid][e] += tv[e];
        }
        __syncthreads();
    }
    int segb[NEXP + 1];
    segb[0] = 0;
    #pragma unroll
    for (int e = 0; e < NEXP; e++) segb[e + 1] = segb[e] + sc2[255][e];
    if (tid == 0) {
        for (int e = 0; e <= NEXP; e++) segPrefix[e] = segb[e];
        int tp = 0;
        tilePrefix[0] = 0;
        for (int e = 0; e < NEXP; e++) {
            tp += (sc2[255][e] + 127) / 128;
            tilePrefix[e + 1] = tp;
        }
    }
    int run[NEXP];
    #pragma unroll
    for (int e = 0; e < NEXP; e++) run[e] = segb[e] + sc2[tid][e] - tt[e];
    #pragma unroll
    for (int j = 0; j < 4; j++)
        #pragma unroll
        for (int e = 0; e < NEXP; e++) {
            int v = blockCounts[(tid * 4 + j) * NEXP + e];
            blockOffsets[(tid * 4 + j) * NEXP + e] = run[e];
            run[e] += v;
        }
}

// ---------------- scatter: Xs[dst(t)] = bf16(x[t] * pmax[t]), expert-sorted stable order
__global__ __launch_bounds__(256) void scatter_kernel(const float* __restrict__ x,
                                                      const int* __restrict__ route,
                                                      const float* __restrict__ pmax,
                                                      const int* __restrict__ blockOffsets,
                                                      unsigned short* __restrict__ Xs) {
    __shared__ int dstL[GB_TOK];
    __shared__ float pmL[GB_TOK];
    int tid = threadIdx.x;
    int bb = blockIdx.x;
    if (tid < GB_TOK) {
        int t = bb * GB_TOK + tid;
        int r = route[t];
        unsigned long long ltmask = (tid == 0) ? 0ull : ((~0ull) >> (64 - tid));
        int rank = 0;
        #pragma unroll
        for (int e = 0; e < NEXP; e++) {
            unsigned long long m = __ballot(r == e);
            if (r == e) rank = __popcll(m & ltmask);
        }
        dstL[tid] = blockOffsets[bb * NEXP + r] + rank;
        pmL[tid] = pmax[t];
    }
    __syncthreads();
    int wave = tid >> 6, lane = tid & 63;
    for (int rr = 0; rr < 4; rr++) {
        int rowl = wave * 4 + rr;
        int t = bb * GB_TOK + rowl;
        float pm = pmL[rowl];
        const float4* xr = (const float4*)(x + (size_t)t * DDIM) + lane * 2;
        float4 a = xr[0], b = xr[1];
        union { short8_t v; unsigned short s[8]; } o;
        o.s[0] = f2bf(a.x * pm); o.s[1] = f2bf(a.y * pm);
        o.s[2] = f2bf(a.z * pm); o.s[3] = f2bf(a.w * pm);
        o.s[4] = f2bf(b.x * pm); o.s[5] = f2bf(b.y * pm);
        o.s[6] = f2bf(b.z * pm); o.s[7] = f2bf(b.w * pm);
        *(short8_t*)(Xs + (size_t)dstL[rowl] * DDIM + lane * 8) = o.v;
    }
}

// ---------------- segmented GEMM, 128x128 tile, BK=64, m-fastest grid (x=m-tile, y=n-tile).
// bf16 output: LDS-repacked coalesced epilogue. f32 output: scalar dword stores (64B segs).
template <bool RELU, typename OutT>
__global__ __launch_bounds__(256) void gemm_seg(const unsigned short* __restrict__ A,
                                                const unsigned short* __restrict__ Bt,
                                                const float* __restrict__ bias,
                                                OutT* __restrict__ C,
                                                const int* __restrict__ segPrefix,
                                                const int* __restrict__ tilePrefix,
                                                int K, int N) {
    int t = blockIdx.x;
    if (t >= tilePrefix[NEXP]) return;
    int e = 0;
    #pragma unroll
    for (int i = 1; i <= NEXP; i++) e += (t >= tilePrefix[i]) ? 1 : 0;
    int seg1 = segPrefix[e + 1];
    int m0 = segPrefix[e] + (t - tilePrefix[e]) * 128;
    int n0 = blockIdx.y * 128;

    __shared__ unsigned short As[2 * 4096];
    __shared__ unsigned short Bs[2 * 4096];

    int tid = threadIdx.x, wave = tid >> 6, lane = tid & 63;
    const unsigned short* Bte = Bt + (size_t)e * N * K;

    int srow = lane >> 2;                                              // row within region
    int sg   = (lane & 3) ^ ((lane >> 2) & 3) ^ ((lane >> 4) & 3);     // swizzled src k-group
    int scol = sg * 8;

    f32x4_t acc[4][4];
    #pragma unroll
    for (int i = 0; i < 4; i++)
        #pragma unroll
        for (int j = 0; j < 4; j++) acc[i][j] = (f32x4_t){0.f, 0.f, 0.f, 0.f};

    int wm = (wave & 1) * 64;
    int wn = (wave >> 1) * 64;
    int frow = lane & 15;
    int gr = lane >> 4;
    int fswz = (gr ^ (frow & 3) ^ ((frow >> 2) & 3)) * 8;   // swizzled k-offset (shorts)

    for (int kc = 0; kc < K; kc += 64) {
        #pragma unroll
        for (int p = 0; p < 2; p++) {
            #pragma unroll
            for (int i = 0; i < 2; i++) {
                int reg = wave * 2 + i;                 // region 0..7
                int arow = m0 + reg * 16 + srow;
                arow = arow < TTOK ? arow : TTOK - 1;   // clamp: masked at store
                gl_lds16(A + (size_t)arow * K + kc + p * 32 + scol, &As[p * 4096 + reg * 512]);
                int brow = n0 + reg * 16 + srow;
                gl_lds16(Bte + (size_t)brow * K + kc + p * 32 + scol, &Bs[p * 4096 + reg * 512]);
            }
        }
        __syncthreads();   // drains vmcnt -> LDS visible
        #pragma unroll
        for (int p = 0; p < 2; p++) {
            short8_t af[4], bfr[4];
            #pragma unroll
            for (int i = 0; i < 4; i++)
                af[i] = *(const short8_t*)&As[p * 4096 + (wm + i * 16 + frow) * 32 + fswz];
            #pragma unroll
            for (int j = 0; j < 4; j++)
                bfr[j] = *(const short8_t*)&Bs[p * 4096 + (wn + j * 16 + frow) * 32 + fswz];
            #pragma unroll
            for (int i = 0; i < 4; i++)
                #pragma unroll
                for (int j = 0; j < 4; j++)
                    acc[i][j] = __builtin_amdgcn_mfma_f32_16x16x32_bf16(af[i], bfr[j], acc[i][j], 0, 0, 0);
        }
        __syncthreads();   // all waves done reading before next overwrite
    }

    int quad = lane >> 4;
    int colb = lane & 15;
    float bv[4];
    #pragma unroll
    for (int j = 0; j < 4; j++) bv[j] = bias[(size_t)e * N + n0 + wn + j * 16 + colb];

    if constexpr (sizeof(OutT) == 2) {
        unsigned short* cbuf = As;   // reuse staging LDS (k-loop fully drained)
        #pragma unroll
        for (int p = 0; p < 2; p++) {
            __syncthreads();
            if ((wave >> 1) == p) {
                #pragma unroll
                for (int i = 0; i < 4; i++)
                    #pragma unroll
                    for (int j = 0; j < 4; j++)
                        #pragma unroll
                        for (int r = 0; r < 4; r++) {
                            float v = acc[i][j][r] + bv[j];
                            if (RELU) v = fmaxf(v, 0.0f);
                            cbuf[(wm + i * 16 + quad * 4 + r) * 72 + j * 16 + colb] = f2bf(v);
                        }
            }
            __syncthreads();
            int row = tid >> 1, ch = (tid & 1) * 32;
            int grow = m0 + row;
            if (grow < seg1) {
                #pragma unroll
                for (int k = 0; k < 4; k++) {
                    short8_t v = *(const short8_t*)&cbuf[row * 72 + ch + k * 8];
                    *(short8_t*)&C[(size_t)grow * N + n0 + p * 64 + ch + k * 8] = v;
                }
            }
        }
    } else {
        #pragma unroll
        for (int i = 0; i < 4; i++) {
            #pragma unroll
            for (int j = 0; j < 4; j++) {
                int col = n0 + wn + j * 16 + colb;
                #pragma unroll
                for (int r = 0; r < 4; r++) {
                    int row = m0 + wm + i * 16 + quad * 4 + r;
                    if (row < seg1) {
                        float v = acc[i][j][r] + bv[j];
                        if (RELU) v = fmaxf(v, 0.0f);
                        C[(size_t)row * N + col] = v;
                    }
                }
            }
        }
    }
}

extern "C" void kernel_launch(void* const* d_in, const int* in_sizes, int n_in,
                              void* d_out, int out_size, void* d_ws, size_t ws_size,
                              hipStream_t stream) {
    const float* x  = (const float*)d_in[0];
    const float* Wg = (const float*)d_in[1];
    const float* bg = (const float*)d_in[2];
    const float* W1 = (const float*)d_in[3];
    const float* b1 = (const float*)d_in[4];
    const float* W2 = (const float*)d_in[5];
    const float* b2 = (const float*)d_in[6];
    float* out = (float*)d_out;

    char* ws = (char*)d_ws;
    size_t off = 0;
    auto alloc = [&](size_t bytes) -> char* {
        char* p = ws + off;
        off += (bytes + 255) & ~(size_t)255;
        return p;
    };
    unsigned short* W1T = (unsigned short*)alloc((size_t)NEXP * DDIM * FFDIM * 2);  // [E][FF][D]
    unsigned short* W2T = (unsigned short*)alloc((size_t)NEXP * DDIM * FFDIM * 2);  // [E][D][FF]
    unsigned short* Xs  = (unsigned short*)alloc((size_t)TTOK * DDIM * 2);          // sorted tokens
    unsigned short* H   = (unsigned short*)alloc((size_t)TTOK * FFDIM * 2);         // hidden
    int*   route        = (int*)alloc((size_t)TTOK * 4);
    float* pmaxArr      = (float*)alloc((size_t)TTOK * 4);
    int*   blockCounts  = (int*)alloc((size_t)NGB * NEXP * 4);
    int*   blockOffsets = (int*)alloc((size_t)NGB * NEXP * 4);
    int*   segPrefix    = (int*)alloc((size_t)(NEXP + 1) * 4);
    int*   tilePrefix   = (int*)alloc((size_t)(NEXP + 1) * 4);
    int*   doneCtr      = (int*)alloc(256);

    // 0: zero the done-counter (ws is poisoned before every call)
    hipMemsetAsync(doneCtr, 0, 4, stream);
    // 1: gating + fused scan (1024 blocks; last block writes offsets/prefixes)
    gate_kernel<<<NGB, 256, 0, stream>>>(x, Wg, bg, route, pmaxArr, blockCounts,
                                         blockOffsets, segPrefix, tilePrefix, doneCtr);
    // 2: permute + scale + cast tokens (x still L3-hot from gate)
    scatter_kernel<<<NGB, 256, 0, stream>>>(x, route, pmaxArr, blockOffsets, Xs);
    // 3: both weight transposes + bf16 cast, vectorized 64x64 tiles
    transpose_cvt2<<<dim3(256, 2 * NEXP), 256, 0, stream>>>(W1, W2, W1T, W2T);
    // 4: H = relu(Xs @ W1[e] + b1[e])  (bf16), 128x128 tiles, m-fastest grid (136, 16)
    gemm_seg<true, unsigned short><<<dim3(MAXTILES, FFDIM / 128, 1), 256, 0, stream>>>(
        Xs, W1T, b1, H, segPrefix, tilePrefix, DDIM, FFDIM);
    // 5: out = H @ W2[e] + b2[e]  (fp32), 128x128 tiles, m-fastest grid (136, 4)
    gemm_seg<false, float><<<dim3(MAXTILES, DDIM / 128, 1), 256, 0, stream>>>(
        H, W2T, b2, out, segPrefix, tilePrefix, FFDIM, DDIM);
}

// Round 7
// 331.522 us; speedup vs baseline: 1.0287x; 1.0287x over previous
//
#include <hip/hip_runtime.h>
#include <hip/hip_bf16.h>

constexpr int TTOK  = 16384;   // B*S = 8*2048
constexpr int DDIM  = 512;
constexpr int FFDIM = 2048;
constexpr int NEXP  = 8;
constexpr int GB_TOK = 16;             // tokens per gate/scatter block
constexpr int NGB    = TTOK / GB_TOK;  // 1024
constexpr int MAXTILES = TTOK / 128 + NEXP;  // 136: worst-case M-tiles over all experts

typedef __attribute__((ext_vector_type(8))) short short8_t;
typedef __attribute__((ext_vector_type(4))) float f32x4_t;

__device__ __forceinline__ unsigned short f2bf(float f) {
    union { float f; unsigned u; } v; v.f = f;
    return (unsigned short)((v.u + 0x7fffu + ((v.u >> 16) & 1u)) >> 16);  // RNE
}

__device__ __forceinline__ void gl_lds16(const void* g, void* l) {
    __builtin_amdgcn_global_load_lds(
        (const __attribute__((address_space(1))) void*)g,
        (__attribute__((address_space(3))) void*)l,
        16, 0, 0);
}

// ---------------- transpose + fp32->bf16 cast, 64x64 tiles, bf16 LDS (8 KB -> high occupancy).
// XOR column swizzle c ^ 8*(r>>3): keeps 4-short writes contiguous, column reads 2-way (free).
// float4 loads; short8 stores, 8 lanes = 128 B segment. grid (256, 16): y<8 = W1, y>=8 = W2.
__global__ __launch_bounds__(256) void transpose_cvt2(const float* __restrict__ W1,
                                                      const float* __restrict__ W2,
                                                      unsigned short* __restrict__ W1T,
                                                      unsigned short* __restrict__ W2T) {
    __shared__ unsigned short lds[64 * 64];   // 8 KB
    int z = blockIdx.y;
    bool isW2 = z >= NEXP;
    int e = isW2 ? z - NEXP : z;
    int R = isW2 ? FFDIM : DDIM;              // source rows  (dst row length)
    int C = isW2 ? DDIM : FFDIM;              // source cols
    int tilesC = C / 64;
    int t = blockIdx.x;                       // 256 tiles per z
    int c0 = (t % tilesC) * 64;
    int r0 = (t / tilesC) * 64;
    const float* s = (isW2 ? W2 : W1) + (size_t)e * DDIM * FFDIM;
    unsigned short* d = (isW2 ? W2T : W1T) + (size_t)e * DDIM * FFDIM;
    int tid = threadIdx.x;
    int lr = tid >> 4, lc = (tid & 15) * 4;
    #pragma unroll
    for (int p = 0; p < 4; p++) {
        int r = p * 16 + lr;
        float4 v = *(const float4*)(s + (size_t)(r0 + r) * C + c0 + lc);
        unsigned short* w = &lds[r * 64 + (lc ^ ((r >> 3) << 3))];
        w[0] = f2bf(v.x); w[1] = f2bf(v.y); w[2] = f2bf(v.z); w[3] = f2bf(v.w);
    }
    __syncthreads();
    int l7 = tid & 7;
    int rr = l7 * 8;
    int cc = tid >> 3;                        // 0..31
    #pragma unroll
    for (int p = 0; p < 2; p++) {
        int c = p * 32 + cc;
        union { short8_t v; unsigned short u[8]; } o;
        #pragma unroll
        for (int k = 0; k < 8; k++)
            o.u[k] = lds[(rr + k) * 64 + (c ^ (l7 << 3))];
        *(short8_t*)(d + (size_t)(c0 + c) * R + r0 + rr) = o.v;
    }
}

// ---------------- gating + fused scan (decoupled last-block pattern).
__global__ __launch_bounds__(256) void gate_kernel(const float* __restrict__ x,
                                                   const float* __restrict__ Wg,
                                                   const float* __restrict__ bg,
                                                   int* __restrict__ route,
                                                   float* __restrict__ pmax,
                                                   int* __restrict__ blockCounts,
                                                   int* __restrict__ blockOffsets,
                                                   int* __restrict__ segPrefix,
                                                   int* __restrict__ tilePrefix,
                                                   int* __restrict__ doneCtr) {
    __shared__ int cnt[NEXP];
    __shared__ float bgs[NEXP];
    __shared__ int sc2[256][NEXP];   // scan workspace (winner block only)
    __shared__ int winner;
    int tid = threadIdx.x;
    if (tid < NEXP) { cnt[tid] = 0; bgs[tid] = bg[tid]; }
    __syncthreads();
    int wave = tid >> 6, lane = tid & 63;
    float w[8][8];
    #pragma unroll
    for (int jj = 0; jj < 8; jj++) {
        float4 a = *(const float4*)(Wg + (size_t)(lane * 8 + jj) * NEXP);
        float4 b = *(const float4*)(Wg + (size_t)(lane * 8 + jj) * NEXP + 4);
        w[jj][0] = a.x; w[jj][1] = a.y; w[jj][2] = a.z; w[jj][3] = a.w;
        w[jj][4] = b.x; w[jj][5] = b.y; w[jj][6] = b.z; w[jj][7] = b.w;
    }
    int tbase = blockIdx.x * GB_TOK + wave * 4;
    for (int it = 0; it < 4; it++) {
        int t = tbase + it;
        float4 xa = *(const float4*)(x + (size_t)t * DDIM + lane * 8);
        float4 xb = *(const float4*)(x + (size_t)t * DDIM + lane * 8 + 4);
        float xs[8] = {xa.x, xa.y, xa.z, xa.w, xb.x, xb.y, xb.z, xb.w};
        double acc[NEXP];
        #pragma unroll
        for (int e = 0; e < NEXP; e++) acc[e] = 0.0;
        #pragma unroll
        for (int jj = 0; jj < 8; jj++) {
            double xv = (double)xs[jj];
            #pragma unroll
            for (int e = 0; e < NEXP; e++) acc[e] += xv * (double)w[jj][e];
        }
        #pragma unroll
        for (int off = 32; off > 0; off >>= 1) {
            #pragma unroll
            for (int e = 0; e < NEXP; e++) acc[e] += __shfl_down(acc[e], off);
        }
        if (lane == 0) {
            double l[NEXP];
            #pragma unroll
            for (int e = 0; e < NEXP; e++) l[e] = acc[e] + (double)bgs[e];
            int r = 0; double lm = l[0];
            #pragma unroll
            for (int e = 1; e < NEXP; e++) if (l[e] > lm) { lm = l[e]; r = e; }
            double s = 0.0;
            #pragma unroll
            for (int e = 0; e < NEXP; e++) s += exp(l[e] - lm);
            route[t] = r;
            pmax[t] = (float)(1.0 / s);
            atomicAdd(&cnt[r], 1);
        }
    }
    __syncthreads();
    if (tid == 0) {
        #pragma unroll
        for (int e = 0; e < NEXP; e++) blockCounts[blockIdx.x * NEXP + e] = cnt[e];
        __threadfence();                                  // publish counts (device scope)
        winner = (atomicAdd(doneCtr, 1) == NGB - 1) ? 1 : 0;
    }
    __syncthreads();
    if (!winner) return;
    __threadfence();                                      // acquire side

    // ---- winner block: scan 1024 x 8 counts with 256 threads (4 blocks/thread)
    int tt[NEXP];
    #pragma unroll
    for (int e = 0; e < NEXP; e++) tt[e] = 0;
    #pragma unroll
    for (int j = 0; j < 4; j++)
        #pragma unroll
        for (int e = 0; e < NEXP; e++) tt[e] += blockCounts[(tid * 4 + j) * NEXP + e];
    #pragma unroll
    for (int e = 0; e < NEXP; e++) sc2[tid][e] = tt[e];
    __syncthreads();
    for (int off = 1; off < 256; off <<= 1) {
        int tv[NEXP];
        bool valid = tid >= off;
        if (valid) {
            #pragma unroll
            for (int e = 0; e < NEXP; e++) tv[e] = sc2[tid - off][e];
        }
        __syncthreads();
        if (valid) {
            #pragma unroll
            for (int e = 0; e < NEXP; e++) sc2[tid][e] += tv[e];
        }
        __syncthreads();
    }
    int segb[NEXP + 1];
    segb[0] = 0;
    #pragma unroll
    for (int e = 0; e < NEXP; e++) segb[e + 1] = segb[e] + sc2[255][e];
    if (tid == 0) {
        for (int e = 0; e <= NEXP; e++) segPrefix[e] = segb[e];
        int tp = 0;
        tilePrefix[0] = 0;
        for (int e = 0; e < NEXP; e++) {
            tp += (sc2[255][e] + 127) / 128;
            tilePrefix[e + 1] = tp;
        }
    }
    int run[NEXP];
    #pragma unroll
    for (int e = 0; e < NEXP; e++) run[e] = segb[e] + sc2[tid][e] - tt[e];
    #pragma unroll
    for (int j = 0; j < 4; j++)
        #pragma unroll
        for (int e = 0; e < NEXP; e++) {
            int v = blockCounts[(tid * 4 + j) * NEXP + e];
            blockOffsets[(tid * 4 + j) * NEXP + e] = run[e];
            run[e] += v;
        }
}

// ---------------- scatter: Xs[dst(t)] = bf16(x[t] * pmax[t]), expert-sorted stable order
__global__ __launch_bounds__(256) void scatter_kernel(const float* __restrict__ x,
                                                      const int* __restrict__ route,
                                                      const float* __restrict__ pmax,
                                                      const int* __restrict__ blockOffsets,
                                                      unsigned short* __restrict__ Xs) {
    __shared__ int dstL[GB_TOK];
    __shared__ float pmL[GB_TOK];
    int tid = threadIdx.x;
    int bb = blockIdx.x;
    if (tid < GB_TOK) {
        int t = bb * GB_TOK + tid;
        int r = route[t];
        unsigned long long ltmask = (tid == 0) ? 0ull : ((~0ull) >> (64 - tid));
        int rank = 0;
        #pragma unroll
        for (int e = 0; e < NEXP; e++) {
            unsigned long long m = __ballot(r == e);
            if (r == e) rank = __popcll(m & ltmask);
        }
        dstL[tid] = blockOffsets[bb * NEXP + r] + rank;
        pmL[tid] = pmax[t];
    }
    __syncthreads();
    int wave = tid >> 6, lane = tid & 63;
    for (int rr = 0; rr < 4; rr++) {
        int rowl = wave * 4 + rr;
        int t = bb * GB_TOK + rowl;
        float pm = pmL[rowl];
        const float4* xr = (const float4*)(x + (size_t)t * DDIM) + lane * 2;
        float4 a = xr[0], b = xr[1];
        union { short8_t v; unsigned short s[8]; } o;
        o.s[0] = f2bf(a.x * pm); o.s[1] = f2bf(a.y * pm);
        o.s[2] = f2bf(a.z * pm); o.s[3] = f2bf(a.w * pm);
        o.s[4] = f2bf(b.x * pm); o.s[5] = f2bf(b.y * pm);
        o.s[6] = f2bf(b.z * pm); o.s[7] = f2bf(b.w * pm);
        *(short8_t*)(Xs + (size_t)dstL[rowl] * DDIM + lane * 8) = o.v;
    }
}

// ---------------- segmented GEMM, 128x128 tile, BK=64, m-fastest grid (x=m-tile, y=n-tile).
// bf16 output: LDS-repacked coalesced epilogue. f32 output: scalar dword stores (64B segs).
template <bool RELU, typename OutT>
__global__ __launch_bounds__(256) void gemm_seg(const unsigned short* __restrict__ A,
                                                const unsigned short* __restrict__ Bt,
                                                const float* __restrict__ bias,
                                                OutT* __restrict__ C,
                                                const int* __restrict__ segPrefix,
                                                const int* __restrict__ tilePrefix,
                                                int K, int N) {
    int t = blockIdx.x;
    if (t >= tilePrefix[NEXP]) return;
    int e = 0;
    #pragma unroll
    for (int i = 1; i <= NEXP; i++) e += (t >= tilePrefix[i]) ? 1 : 0;
    int seg1 = segPrefix[e + 1];
    int m0 = segPrefix[e] + (t - tilePrefix[e]) * 128;
    int n0 = blockIdx.y * 128;

    __shared__ unsigned short As[2 * 4096];
    __shared__ unsigned short Bs[2 * 4096];

    int tid = threadIdx.x, wave = tid >> 6, lane = tid & 63;
    const unsigned short* Bte = Bt + (size_t)e * N * K;

    int srow = lane >> 2;                                              // row within region
    int sg   = (lane & 3) ^ ((lane >> 2) & 3) ^ ((lane >> 4) & 3);     // swizzled src k-group
    int scol = sg * 8;

    f32x4_t acc[4][4];
    #pragma unroll
    for (int i = 0; i < 4; i++)
        #pragma unroll
        for (int j = 0; j < 4; j++) acc[i][j] = (f32x4_t){0.f, 0.f, 0.f, 0.f};

    int wm = (wave & 1) * 64;
    int wn = (wave >> 1) * 64;
    int frow = lane & 15;
    int gr = lane >> 4;
    int fswz = (gr ^ (frow & 3) ^ ((frow >> 2) & 3)) * 8;   // swizzled k-offset (shorts)

    for (int kc = 0; kc < K; kc += 64) {
        #pragma unroll
        for (int p = 0; p < 2; p++) {
            #pragma unroll
            for (int i = 0; i < 2; i++) {
                int reg = wave * 2 + i;                 // region 0..7
                int arow = m0 + reg * 16 + srow;
                arow = arow < TTOK ? arow : TTOK - 1;   // clamp: masked at store
                gl_lds16(A + (size_t)arow * K + kc + p * 32 + scol, &As[p * 4096 + reg * 512]);
                int brow = n0 + reg * 16 + srow;
                gl_lds16(Bte + (size_t)brow * K + kc + p * 32 + scol, &Bs[p * 4096 + reg * 512]);
            }
        }
        __syncthreads();   // drains vmcnt -> LDS visible
        #pragma unroll
        for (int p = 0; p < 2; p++) {
            short8_t af[4], bfr[4];
            #pragma unroll
            for (int i = 0; i < 4; i++)
                af[i] = *(const short8_t*)&As[p * 4096 + (wm + i * 16 + frow) * 32 + fswz];
            #pragma unroll
            for (int j = 0; j < 4; j++)
                bfr[j] = *(const short8_t*)&Bs[p * 4096 + (wn + j * 16 + frow) * 32 + fswz];
            #pragma unroll
            for (int i = 0; i < 4; i++)
                #pragma unroll
                for (int j = 0; j < 4; j++)
                    acc[i][j] = __builtin_amdgcn_mfma_f32_16x16x32_bf16(af[i], bfr[j], acc[i][j], 0, 0, 0);
        }
        __syncthreads();   // all waves done reading before next overwrite
    }

    int quad = lane >> 4;
    int colb = lane & 15;
    float bv[4];
    #pragma unroll
    for (int j = 0; j < 4; j++) bv[j] = bias[(size_t)e * N + n0 + wn + j * 16 + colb];

    if constexpr (sizeof(OutT) == 2) {
        unsigned short* cbuf = As;   // reuse staging LDS (k-loop fully drained)
        #pragma unroll
        for (int p = 0; p < 2; p++) {
            __syncthreads();
            if ((wave >> 1) == p) {
                #pragma unroll
                for (int i = 0; i < 4; i++)
                    #pragma unroll
                    for (int j = 0; j < 4; j++)
                        #pragma unroll
                        for (int r = 0; r < 4; r++) {
                            float v = acc[i][j][r] + bv[j];
                            if (RELU) v = fmaxf(v, 0.0f);
                            cbuf[(wm + i * 16 + quad * 4 + r) * 72 + j * 16 + colb] = f2bf(v);
                        }
            }
            __syncthreads();
            int row = tid >> 1, ch = (tid & 1) * 32;
            int grow = m0 + row;
            if (grow < seg1) {
                #pragma unroll
                for (int k = 0; k < 4; k++) {
                    short8_t v = *(const short8_t*)&cbuf[row * 72 + ch + k * 8];
                    *(short8_t*)&C[(size_t)grow * N + n0 + p * 64 + ch + k * 8] = v;
                }
            }
        }
    } else {
        #pragma unroll
        for (int i = 0; i < 4; i++) {
            #pragma unroll
            for (int j = 0; j < 4; j++) {
                int col = n0 + wn + j * 16 + colb;
                #pragma unroll
                for (int r = 0; r < 4; r++) {
                    int row = m0 + wm + i * 16 + quad * 4 + r;
                    if (row < seg1) {
                        float v = acc[i][j][r] + bv[j];
                        if (RELU) v = fmaxf(v, 0.0f);
                        C[(size_t)row * N + col] = v;
                    }
                }
            }
        }
    }
}

extern "C" void kernel_launch(void* const* d_in, const int* in_sizes, int n_in,
                              void* d_out, int out_size, void* d_ws, size_t ws_size,
                              hipStream_t stream) {
    const float* x  = (const float*)d_in[0];
    const float* Wg = (const float*)d_in[1];
    const float* bg = (const float*)d_in[2];
    const float* W1 = (const float*)d_in[3];
    const float* b1 = (const float*)d_in[4];
    const float* W2 = (const float*)d_in[5];
    const float* b2 = (const float*)d_in[6];
    float* out = (float*)d_out;

    char* ws = (char*)d_ws;
    size_t off = 0;
    auto alloc = [&](size_t bytes) -> char* {
        char* p = ws + off;
        off += (bytes + 255) & ~(size_t)255;
        return p;
    };
    unsigned short* W1T = (unsigned short*)alloc((size_t)NEXP * DDIM * FFDIM * 2);  // [E][FF][D]
    unsigned short* W2T = (unsigned short*)alloc((size_t)NEXP * DDIM * FFDIM * 2);  // [E][D][FF]
    unsigned short* Xs  = (unsigned short*)alloc((size_t)TTOK * DDIM * 2);          // sorted tokens
    unsigned short* H   = (unsigned short*)alloc((size_t)TTOK * FFDIM * 2);         // hidden
    int*   route        = (int*)alloc((size_t)TTOK * 4);
    float* pmaxArr      = (float*)alloc((size_t)TTOK * 4);
    int*   blockCounts  = (int*)alloc((size_t)NGB * NEXP * 4);
    int*   blockOffsets = (int*)alloc((size_t)NGB * NEXP * 4);
    int*   segPrefix    = (int*)alloc((size_t)(NEXP + 1) * 4);
    int*   tilePrefix   = (int*)alloc((size_t)(NEXP + 1) * 4);
    int*   doneCtr      = (int*)alloc(256);

    // 0: zero the done-counter (ws is poisoned before every call)
    hipMemsetAsync(doneCtr, 0, 4, stream);
    // 1: both weight transposes + bf16 cast (bf16 LDS, high occupancy)
    transpose_cvt2<<<dim3(256, 2 * NEXP), 256, 0, stream>>>(W1, W2, W1T, W2T);
    // 2: gating + fused scan (1024 blocks; last block writes offsets/prefixes)
    gate_kernel<<<NGB, 256, 0, stream>>>(x, Wg, bg, route, pmaxArr, blockCounts,
                                         blockOffsets, segPrefix, tilePrefix, doneCtr);
    // 3: permute + scale + cast tokens (x L3-hot from gate)
    scatter_kernel<<<NGB, 256, 0, stream>>>(x, route, pmaxArr, blockOffsets, Xs);
    // 4: H = relu(Xs @ W1[e] + b1[e])  (bf16), 128x128 tiles, m-fastest grid (136, 16)
    gemm_seg<true, unsigned short><<<dim3(MAXTILES, FFDIM / 128, 1), 256, 0, stream>>>(
        Xs, W1T, b1, H, segPrefix, tilePrefix, DDIM, FFDIM);
    // 5: out = H @ W2[e] + b2[e]  (fp32), 128x128 tiles, m-fastest grid (136, 4)
    gemm_seg<false, float><<<dim3(MAXTILES, DDIM / 128, 1), 256, 0, stream>>>(
        H, W2T, b2, out, segPrefix, tilePrefix, FFDIM, DDIM);
}

// Round 8
// 311.840 us; speedup vs baseline: 1.0936x; 1.0631x over previous
//
#include <hip/hip_runtime.h>
#include <hip/hip_bf16.h>

constexpr int TTOK  = 16384;   // B*S = 8*2048
constexpr int DDIM  = 512;
constexpr int FFDIM = 2048;
constexpr int NEXP  = 8;
constexpr int GB_TOK = 16;             // tokens per gate/scatter block
constexpr int NGB    = TTOK / GB_TOK;  // 1024
constexpr int MAXTILES = TTOK / 128 + NEXP;  // 136: worst-case M-tiles over all experts

typedef __attribute__((ext_vector_type(8))) short short8_t;
typedef __attribute__((ext_vector_type(4))) float f32x4_t;

__device__ __forceinline__ unsigned short f2bf(float f) {
    union { float f; unsigned u; } v; v.f = f;
    return (unsigned short)((v.u + 0x7fffu + ((v.u >> 16) & 1u)) >> 16);  // RNE
}

__device__ __forceinline__ void gl_lds16(const void* g, void* l) {
    __builtin_amdgcn_global_load_lds(
        (const __attribute__((address_space(1))) void*)g,
        (__attribute__((address_space(3))) void*)l,
        16, 0, 0);
}

// ---------------- transpose + fp32->bf16 cast:  src [E][R][C] f32 -> dst [E][C][R] bf16
// (R5 version: 32x32 tiles, 4 KB LDS, high occupancy — measured-good)
__global__ __launch_bounds__(256) void transpose_cvt2(const float* __restrict__ W1,
                                                      const float* __restrict__ W2,
                                                      unsigned short* __restrict__ W1T,
                                                      unsigned short* __restrict__ W2T) {
    __shared__ float tile[32][33];
    int z = blockIdx.z;
    bool isW2 = z >= NEXP;
    int e = isW2 ? z - NEXP : z;
    int R = isW2 ? FFDIM : DDIM;
    int C = isW2 ? DDIM : FFDIM;
    int tilesC = C / 32;
    int t = blockIdx.x;                    // 1024 tiles either way
    int c0 = (t % tilesC) * 32;
    int r0 = (t / tilesC) * 32;
    const float* s = (isW2 ? W2 : W1) + (size_t)e * DDIM * FFDIM;
    unsigned short* d = (isW2 ? W2T : W1T) + (size_t)e * DDIM * FFDIM;
    int tx = threadIdx.x & 31, ty = threadIdx.x >> 5;   // 32 x 8
    #pragma unroll
    for (int i = 0; i < 4; i++)
        tile[ty + 8 * i][tx] = s[(size_t)(r0 + ty + 8 * i) * C + c0 + tx];
    __syncthreads();
    #pragma unroll
    for (int i = 0; i < 4; i++)
        d[(size_t)(c0 + ty + 8 * i) * R + r0 + tx] = f2bf(tile[tx][ty + 8 * i]);
}

// ---------------- gating: Wg in registers, f64 accum, 1024 blocks x 16 tokens (R5 version)
__global__ __launch_bounds__(256) void gate_kernel(const float* __restrict__ x,
                                                   const float* __restrict__ Wg,
                                                   const float* __restrict__ bg,
                                                   int* __restrict__ route,
                                                   float* __restrict__ pmax,
                                                   int* __restrict__ blockCounts) {
    __shared__ int cnt[NEXP];
    __shared__ float bgs[NEXP];
    int tid = threadIdx.x;
    if (tid < NEXP) { cnt[tid] = 0; bgs[tid] = bg[tid]; }
    __syncthreads();
    int wave = tid >> 6, lane = tid & 63;
    float w[8][8];
    #pragma unroll
    for (int jj = 0; jj < 8; jj++) {
        float4 a = *(const float4*)(Wg + (size_t)(lane * 8 + jj) * NEXP);
        float4 b = *(const float4*)(Wg + (size_t)(lane * 8 + jj) * NEXP + 4);
        w[jj][0] = a.x; w[jj][1] = a.y; w[jj][2] = a.z; w[jj][3] = a.w;
        w[jj][4] = b.x; w[jj][5] = b.y; w[jj][6] = b.z; w[jj][7] = b.w;
    }
    int tbase = blockIdx.x * GB_TOK + wave * 4;
    for (int it = 0; it < 4; it++) {
        int t = tbase + it;
        float4 xa = *(const float4*)(x + (size_t)t * DDIM + lane * 8);
        float4 xb = *(const float4*)(x + (size_t)t * DDIM + lane * 8 + 4);
        float xs[8] = {xa.x, xa.y, xa.z, xa.w, xb.x, xb.y, xb.z, xb.w};
        double acc[NEXP];
        #pragma unroll
        for (int e = 0; e < NEXP; e++) acc[e] = 0.0;
        #pragma unroll
        for (int jj = 0; jj < 8; jj++) {
            double xv = (double)xs[jj];
            #pragma unroll
            for (int e = 0; e < NEXP; e++) acc[e] += xv * (double)w[jj][e];
        }
        #pragma unroll
        for (int off = 32; off > 0; off >>= 1) {
            #pragma unroll
            for (int e = 0; e < NEXP; e++) acc[e] += __shfl_down(acc[e], off);
        }
        if (lane == 0) {
            double l[NEXP];
            #pragma unroll
            for (int e = 0; e < NEXP; e++) l[e] = acc[e] + (double)bgs[e];
            int r = 0; double lm = l[0];
            #pragma unroll
            for (int e = 1; e < NEXP; e++) if (l[e] > lm) { lm = l[e]; r = e; }
            double s = 0.0;
            #pragma unroll
            for (int e = 0; e < NEXP; e++) s += exp(l[e] - lm);
            route[t] = r;
            pmax[t] = (float)(1.0 / s);
            atomicAdd(&cnt[r], 1);
        }
    }
    __syncthreads();
    if (tid < NEXP) blockCounts[blockIdx.x * NEXP + tid] = cnt[tid];
}

// ---------------- single-block scan (1024 thr) -> stable counting-sort offsets + tile lists
__global__ __launch_bounds__(1024) void scan_kernel(const int* __restrict__ blockCounts,
                                                    int* __restrict__ blockOffsets,
                                                    int* __restrict__ segPrefix,
                                                    int* __restrict__ tilePrefix) {
    __shared__ int sc[NGB][NEXP];
    __shared__ int base[NEXP + 1];
    int b = threadIdx.x;
    int c[NEXP];
    #pragma unroll
    for (int e = 0; e < NEXP; e++) { c[e] = blockCounts[b * NEXP + e]; sc[b][e] = c[e]; }
    __syncthreads();
    for (int off = 1; off < NGB; off <<= 1) {
        int t[NEXP];
        if (b >= off) {
            #pragma unroll
            for (int e = 0; e < NEXP; e++) t[e] = sc[b - off][e];
        }
        __syncthreads();
        if (b >= off) {
            #pragma unroll
            for (int e = 0; e < NEXP; e++) sc[b][e] += t[e];
        }
        __syncthreads();
    }
    if (b == 0) {
        int s = 0;
        #pragma unroll
        for (int e = 0; e < NEXP; e++) { base[e] = s; s += sc[NGB - 1][e]; }
        base[NEXP] = s;
        for (int e = 0; e <= NEXP; e++) segPrefix[e] = base[e];
        int tp = 0;
        tilePrefix[0] = 0;
        for (int e = 0; e < NEXP; e++) {
            tp += (sc[NGB - 1][e] + 127) / 128;
            tilePrefix[e + 1] = tp;
        }
    }
    __syncthreads();
    #pragma unroll
    for (int e = 0; e < NEXP; e++)
        blockOffsets[b * NEXP + e] = base[e] + sc[b][e] - c[e];
}

// ---------------- scatter: Xs[dst(t)] = bf16(x[t] * pmax[t]), expert-sorted stable order
__global__ __launch_bounds__(256) void scatter_kernel(const float* __restrict__ x,
                                                      const int* __restrict__ route,
                                                      const float* __restrict__ pmax,
                                                      const int* __restrict__ blockOffsets,
                                                      unsigned short* __restrict__ Xs) {
    __shared__ int dstL[GB_TOK];
    __shared__ float pmL[GB_TOK];
    int tid = threadIdx.x;
    int bb = blockIdx.x;
    if (tid < GB_TOK) {
        int t = bb * GB_TOK + tid;
        int r = route[t];
        unsigned long long ltmask = (tid == 0) ? 0ull : ((~0ull) >> (64 - tid));
        int rank = 0;
        #pragma unroll
        for (int e = 0; e < NEXP; e++) {
            unsigned long long m = __ballot(r == e);
            if (r == e) rank = __popcll(m & ltmask);
        }
        dstL[tid] = blockOffsets[bb * NEXP + r] + rank;
        pmL[tid] = pmax[t];
    }
    __syncthreads();
    int wave = tid >> 6, lane = tid & 63;
    for (int rr = 0; rr < 4; rr++) {
        int rowl = wave * 4 + rr;
        int t = bb * GB_TOK + rowl;
        float pm = pmL[rowl];
        const float4* xr = (const float4*)(x + (size_t)t * DDIM) + lane * 2;
        float4 a = xr[0], b = xr[1];
        union { short8_t v; unsigned short s[8]; } o;
        o.s[0] = f2bf(a.x * pm); o.s[1] = f2bf(a.y * pm);
        o.s[2] = f2bf(a.z * pm); o.s[3] = f2bf(a.w * pm);
        o.s[4] = f2bf(b.x * pm); o.s[5] = f2bf(b.y * pm);
        o.s[6] = f2bf(b.z * pm); o.s[7] = f2bf(b.w * pm);
        *(short8_t*)(Xs + (size_t)dstL[rowl] * DDIM + lane * 8) = o.v;
    }
}

// ---------------- segmented GEMM, 128x128 tile, BK=64, m-fastest grid (x=m-tile, y=n-tile).
// K, N are COMPILE-TIME: strides become shift immediates, K-loop fully unrolls,
// per-iter address chains fold into instruction offsets (attacks VALUBusy>MfmaUtil).
template <bool RELU, typename OutT, int K, int N>
__global__ __launch_bounds__(256) void gemm_seg(const unsigned short* __restrict__ A,
                                                const unsigned short* __restrict__ Bt,
                                                const float* __restrict__ bias,
                                                OutT* __restrict__ C,
                                                const int* __restrict__ segPrefix,
                                                const int* __restrict__ tilePrefix) {
    int t = blockIdx.x;
    if (t >= tilePrefix[NEXP]) return;
    int e = 0;
    #pragma unroll
    for (int i = 1; i <= NEXP; i++) e += (t >= tilePrefix[i]) ? 1 : 0;
    int seg1 = segPrefix[e + 1];
    int m0 = segPrefix[e] + (t - tilePrefix[e]) * 128;
    int n0 = blockIdx.y * 128;

    __shared__ unsigned short As[2 * 4096];
    __shared__ unsigned short Bs[2 * 4096];

    int tid = threadIdx.x, wave = tid >> 6, lane = tid & 63;
    const unsigned short* Bte = Bt + (size_t)e * N * K;

    int srow = lane >> 2;                                              // row within region
    int sg   = (lane & 3) ^ ((lane >> 2) & 3) ^ ((lane >> 4) & 3);     // swizzled src k-group
    int scol = sg * 8;

    f32x4_t acc[4][4];
    #pragma unroll
    for (int i = 0; i < 4; i++)
        #pragma unroll
        for (int j = 0; j < 4; j++) acc[i][j] = (f32x4_t){0.f, 0.f, 0.f, 0.f};

    int wm = (wave & 1) * 64;
    int wn = (wave >> 1) * 64;
    int frow = lane & 15;
    int gr = lane >> 4;
    int fswz = (gr ^ (frow & 3) ^ ((frow >> 2) & 3)) * 8;   // swizzled k-offset (shorts)

    // base pointers hoisted; per-iter offset is a compile-time constant
    int reg0 = wave * 2;
    int arow0 = m0 + reg0 * 16 + srow;
    arow0 = arow0 < TTOK ? arow0 : TTOK - 1;
    int arow1 = m0 + (reg0 + 1) * 16 + srow;
    arow1 = arow1 < TTOK ? arow1 : TTOK - 1;
    const unsigned short* aptr0 = A + (size_t)arow0 * K + scol;
    const unsigned short* aptr1 = A + (size_t)arow1 * K + scol;
    const unsigned short* bptr0 = Bte + (size_t)(n0 + reg0 * 16 + srow) * K + scol;
    const unsigned short* bptr1 = Bte + (size_t)(n0 + (reg0 + 1) * 16 + srow) * K + scol;

    #pragma unroll
    for (int kc = 0; kc < K; kc += 64) {
        #pragma unroll
        for (int p = 0; p < 2; p++) {
            gl_lds16(aptr0 + kc + p * 32, &As[p * 4096 + reg0 * 512]);
            gl_lds16(aptr1 + kc + p * 32, &As[p * 4096 + (reg0 + 1) * 512]);
            gl_lds16(bptr0 + kc + p * 32, &Bs[p * 4096 + reg0 * 512]);
            gl_lds16(bptr1 + kc + p * 32, &Bs[p * 4096 + (reg0 + 1) * 512]);
        }
        __syncthreads();   // drains vmcnt -> LDS visible
        #pragma unroll
        for (int p = 0; p < 2; p++) {
            short8_t af[4], bfr[4];
            #pragma unroll
            for (int i = 0; i < 4; i++)
                af[i] = *(const short8_t*)&As[p * 4096 + (wm + i * 16 + frow) * 32 + fswz];
            #pragma unroll
            for (int j = 0; j < 4; j++)
                bfr[j] = *(const short8_t*)&Bs[p * 4096 + (wn + j * 16 + frow) * 32 + fswz];
            #pragma unroll
            for (int i = 0; i < 4; i++)
                #pragma unroll
                for (int j = 0; j < 4; j++)
                    acc[i][j] = __builtin_amdgcn_mfma_f32_16x16x32_bf16(af[i], bfr[j], acc[i][j], 0, 0, 0);
        }
        __syncthreads();   // all waves done reading before next overwrite
    }

    int quad = lane >> 4;
    int colb = lane & 15;
    float bv[4];
    #pragma unroll
    for (int j = 0; j < 4; j++) bv[j] = bias[(size_t)e * N + n0 + wn + j * 16 + colb];

    if constexpr (sizeof(OutT) == 2) {
        unsigned short* cbuf = As;   // reuse staging LDS (k-loop fully drained)
        #pragma unroll
        for (int p = 0; p < 2; p++) {
            __syncthreads();
            if ((wave >> 1) == p) {
                #pragma unroll
                for (int i = 0; i < 4; i++)
                    #pragma unroll
                    for (int j = 0; j < 4; j++)
                        #pragma unroll
                        for (int r = 0; r < 4; r++) {
                            float v = acc[i][j][r] + bv[j];
                            if (RELU) v = fmaxf(v, 0.0f);
                            cbuf[(wm + i * 16 + quad * 4 + r) * 72 + j * 16 + colb] = f2bf(v);
                        }
            }
            __syncthreads();
            int row = tid >> 1, ch = (tid & 1) * 32;
            int grow = m0 + row;
            if (grow < seg1) {
                #pragma unroll
                for (int k = 0; k < 4; k++) {
                    short8_t v = *(const short8_t*)&cbuf[row * 72 + ch + k * 8];
                    *(short8_t*)&C[(size_t)grow * N + n0 + p * 64 + ch + k * 8] = v;
                }
            }
        }
    } else {
        #pragma unroll
        for (int i = 0; i < 4; i++) {
            #pragma unroll
            for (int j = 0; j < 4; j++) {
                int col = n0 + wn + j * 16 + colb;
                #pragma unroll
                for (int r = 0; r < 4; r++) {
                    int row = m0 + wm + i * 16 + quad * 4 + r;
                    if (row < seg1) {
                        float v = acc[i][j][r] + bv[j];
                        if (RELU) v = fmaxf(v, 0.0f);
                        C[(size_t)row * N + col] = v;
                    }
                }
            }
        }
    }
}

extern "C" void kernel_launch(void* const* d_in, const int* in_sizes, int n_in,
                              void* d_out, int out_size, void* d_ws, size_t ws_size,
                              hipStream_t stream) {
    const float* x  = (const float*)d_in[0];
    const float* Wg = (const float*)d_in[1];
    const float* bg = (const float*)d_in[2];
    const float* W1 = (const float*)d_in[3];
    const float* b1 = (const float*)d_in[4];
    const float* W2 = (const float*)d_in[5];
    const float* b2 = (const float*)d_in[6];
    float* out = (float*)d_out;

    char* ws = (char*)d_ws;
    size_t off = 0;
    auto alloc = [&](size_t bytes) -> char* {
        char* p = ws + off;
        off += (bytes + 255) & ~(size_t)255;
        return p;
    };
    unsigned short* W1T = (unsigned short*)alloc((size_t)NEXP * DDIM * FFDIM * 2);  // [E][FF][D]
    unsigned short* W2T = (unsigned short*)alloc((size_t)NEXP * DDIM * FFDIM * 2);  // [E][D][FF]
    unsigned short* Xs  = (unsigned short*)alloc((size_t)TTOK * DDIM * 2);          // sorted tokens
    unsigned short* H   = (unsigned short*)alloc((size_t)TTOK * FFDIM * 2);         // hidden
    int*   route        = (int*)alloc((size_t)TTOK * 4);
    float* pmaxArr      = (float*)alloc((size_t)TTOK * 4);
    int*   blockCounts  = (int*)alloc((size_t)NGB * NEXP * 4);
    int*   blockOffsets = (int*)alloc((size_t)NGB * NEXP * 4);
    int*   segPrefix    = (int*)alloc((size_t)(NEXP + 1) * 4);
    int*   tilePrefix   = (int*)alloc((size_t)(NEXP + 1) * 4);

    // 1: both weight transposes + bf16 cast (R5 32x32 version)
    transpose_cvt2<<<dim3(1024, 1, 2 * NEXP), 256, 0, stream>>>(W1, W2, W1T, W2T);
    // 2: gating (1024 blocks)
    gate_kernel<<<NGB, 256, 0, stream>>>(x, Wg, bg, route, pmaxArr, blockCounts);
    // 3: scan -> stable sort offsets + tile lists
    scan_kernel<<<1, NGB, 0, stream>>>(blockCounts, blockOffsets, segPrefix, tilePrefix);
    // 4: permute + scale + cast tokens (1024 blocks)
    scatter_kernel<<<NGB, 256, 0, stream>>>(x, route, pmaxArr, blockOffsets, Xs);
    // 5: H = relu(Xs @ W1[e] + b1[e])  (bf16), 128x128 tiles, m-fastest grid (136, 16)
    gemm_seg<true, unsigned short, DDIM, FFDIM><<<dim3(MAXTILES, FFDIM / 128, 1), 256, 0, stream>>>(
        Xs, W1T, b1, H, segPrefix, tilePrefix);
    // 6: out = H @ W2[e] + b2[e]  (fp32), 128x128 tiles, m-fastest grid (136, 4)
    gemm_seg<false, float, FFDIM, DDIM><<<dim3(MAXTILES, DDIM / 128, 1), 256, 0, stream>>>(
        H, W2T, b2, out, segPrefix, tilePrefix);
}